// Round 17
// baseline (348.273 us; speedup 1.0000x reference)
//
#include <hip/hip_runtime.h>
#include <hip/hip_bf16.h>
#include <math.h>
#include <stdint.h>

#define NTOK 21824
#define NTILE 341        // 64-token tiles; NTOK = 341*64 exactly (no tail)

typedef __attribute__((ext_vector_type(8)))  short bf16x8;
typedef __attribute__((ext_vector_type(4)))  float f32x4;
typedef __attribute__((ext_vector_type(16))) float f32x16;

__device__ __forceinline__ uint32_t f2bf(float f) {
    uint32_t u = __builtin_bit_cast(uint32_t, f);
    return (u + 0x7FFFu + ((u >> 16) & 1u)) >> 16;   // RNE
}
__device__ __forceinline__ uint32_t pkbf2(float lo, float hi) {
    __hip_bfloat162 h = __float22bfloat162_rn(float2{lo, hi});
    uint32_t r; __builtin_memcpy(&r, &h, 4);         // v_cvt_pk_bf16_f32
    return r;
}

// ws layout (uint16): cls_Wh @0, box_Wh @65536, cls_Wo @131072, box_Wo(pad 16x256) @151552
#define WOFF_CWH 0
#define WOFF_BWH 65536
#define WOFF_CWO 131072
#define WOFF_BWO 151552

__global__ void prep_weights(const float* __restrict__ cWh, const float* __restrict__ cWo,
                             const float* __restrict__ bWh, const float* __restrict__ bWo,
                             uint16_t* __restrict__ ws) {
    int i = blockIdx.x * 256 + threadIdx.x;
    if (i >= 155648) return;
    uint32_t v;
    if (i < 65536)       v = f2bf(cWh[i]);
    else if (i < 131072) v = f2bf(bWh[i - 65536]);
    else if (i < 151552) v = f2bf(cWo[i - 131072]);
    else { int j = i - 151552; v = (j < 1024) ? f2bf(bWo[j]) : 0u; }
    ws[i] = (uint16_t)v;
}

// Block = (64-token tile, head) x 4 batches. 8 waves.
// Wave's G1 weight slice (16 KB) register-resident across all 4 batches ->
// zero vmem in the G1 inner loop. Xs/Hs separate (32+32 KB) -> 2 barriers/iter.
__global__ __launch_bounds__(512, 4) void dfd_head(
    const float* __restrict__ fm0, const float* __restrict__ fm1,
    const float* __restrict__ fm2, const float* __restrict__ fm3,
    const float* __restrict__ fm4,
    const float* __restrict__ cls_bh, const float* __restrict__ cls_bo,
    const float* __restrict__ box_bh, const float* __restrict__ box_bo,
    const uint16_t* __restrict__ wbf,
    float* __restrict__ out)
{
    // (tile, head): twins (s, s+8) share id%8 -> same XCD for X L2 sharing
    const int g    = blockIdx.x;
    const int s    = g & 15;
    const int tile = (g >> 4) * 8 + (s & 7);
    const int head = s >> 3;                 // 0 = cls, 1 = box
    if (tile >= NTILE) return;               // block-uniform

    __shared__ uint16_t Xs[64 * 256];        // 32 KB, swizzle f ^ ((t&31)<<3)
    __shared__ uint16_t Hs[64 * 256];        // 32 KB, swizzle h ^ ((t&15)<<4)

    const int tid  = threadIdx.x;
    const int lane = tid & 63;
    const int w    = tid >> 6;               // wave 0..7
    const int r    = lane & 15;
    const int q    = lane >> 4;
    const int col  = lane & 31;
    const int hi   = lane >> 5;
    const int n0   = tile * 64;
    const int b0   = blockIdx.y * 4;         // 4 batches per block

    const float* fm; int off, ls;
    if      (n0 < 16384) { fm = fm0; off = 0;     ls = 7; }
    else if (n0 < 20480) { fm = fm1; off = 16384; ls = 6; }
    else if (n0 < 21504) { fm = fm2; off = 20480; ls = 5; }
    else if (n0 < 21760) { fm = fm3; off = 21504; ls = 4; }
    else                 { fm = fm4; off = 21760; ls = 3; }
    const int dim = 1 << ls;
    const int hw  = 1 << (2 * ls);
    const int p0  = n0 - off;

    // ---- hoist G1 weights: wave w owns hh [w*32, w*32+32); 16 frags = 64 VGPR
    const int hhw = w * 32;
    const int kh  = hi * 8;
    const uint16_t* Wr = wbf + (head ? WOFF_BWH : WOFF_CWH) + (hhw + col) * 256 + kh;
    bf16x8 Wf[16];
    #pragma unroll
    for (int ks = 0; ks < 16; ++ks) Wf[ks] = *(const bf16x8*)(Wr + ks * 16);

    const int sw0 = col << 3;
    const float* bh_ = (head ? box_bh : cls_bh) + hhw;

    for (int lb = 0; lb < 4; ++lb) {
        const int b = b0 + lb;

        // ---- stage: fm[b][f][p0+t] -> Xs[t][f^sw]; t = tid&63, fg = w covers 32 f
        {
            const int t  = tid & 63;
            const int sw = (t & 31) << 3;
            const float* src = fm + (size_t)b * 256 * hw + p0 + t;
            #pragma unroll
            for (int i = 0; i < 4; ++i) {
                const int f0 = w * 32 + i * 8;
                float x[8];
                #pragma unroll
                for (int e = 0; e < 8; ++e) x[e] = src[(size_t)(f0 + e) * hw];
                uint4 pk;
                pk.x = pkbf2(x[0], x[1]); pk.y = pkbf2(x[2], x[3]);
                pk.z = pkbf2(x[4], x[5]); pk.w = pkbf2(x[6], x[7]);
                *reinterpret_cast<uint4*>(&Xs[t * 256 + (f0 ^ sw)]) = pk;
            }
        }
        __syncthreads();   // barrier 1: Xs ready (also fences G2(prev) Hs reads)

        // ---- G1 (32x32x16): C[h][t], ZERO vmem in the loop (r15-verified mapping)
        f32x16 acc[2];     // [nt = token 32-tile] = 32 AGPR
        #pragma unroll
        for (int nt = 0; nt < 2; ++nt)
            #pragma unroll
            for (int e = 0; e < 16; ++e) acc[nt][e] = 0.f;

        #pragma unroll
        for (int ks = 0; ks < 16; ++ks) {
            const int kx = (ks * 16 + kh) ^ sw0;
            const bf16x8 x0 = *(const bf16x8*)&Xs[col * 256 + kx];
            const bf16x8 x1 = *(const bf16x8*)&Xs[(32 + col) * 256 + kx];
            acc[0] = __builtin_amdgcn_mfma_f32_32x32x16_bf16(Wf[ks], x0, acc[0], 0, 0, 0);
            acc[1] = __builtin_amdgcn_mfma_f32_32x32x16_bf16(Wf[ks], x1, acc[1], 0, 0, 0);
        }

        // ---- epilogue: bias+ReLU -> Hs (separate buffer; no Xs-read hazard)
        #pragma unroll
        for (int nt = 0; nt < 2; ++nt) {
            const int t   = nt * 32 + col;
            const int swt = (t & 15) << 4;
            #pragma unroll
            for (int g2 = 0; g2 < 4; ++g2) {
                const int hb = 8 * g2 + 4 * hi;      // C row = hb + (reg&3)
                const f32x4 bv = *(const f32x4*)(bh_ + hb);
                const float v0 = fmaxf(acc[nt][4 * g2 + 0] + bv[0], 0.f);
                const float v1 = fmaxf(acc[nt][4 * g2 + 1] + bv[1], 0.f);
                const float v2 = fmaxf(acc[nt][4 * g2 + 2] + bv[2], 0.f);
                const float v3 = fmaxf(acc[nt][4 * g2 + 3] + bv[3], 0.f);
                uint2 pk; pk.x = pkbf2(v0, v1); pk.y = pkbf2(v2, v3);
                *reinterpret_cast<uint2*>(&Hs[t * 256 + ((hhw + hb) ^ swt)]) = pk;
            }
        }
        __syncthreads();   // barrier 2: Hs ready

        // ---- G2 (16x16x32), r15-verified mappings, 4 token-tiles
        if (head == 0) {
            if (w < 5) {
                const uint16_t* Bw = wbf + WOFF_CWO + (w * 16 + r) * 256 + q * 8;
                bf16x8 bfr[8];
                #pragma unroll
                for (int kq = 0; kq < 8; ++kq) bfr[kq] = *(const bf16x8*)(Bw + kq * 32);
                const float bo_l = cls_bo[w * 16 + r];
                #pragma unroll
                for (int tt = 0; tt < 4; ++tt) {
                    const int tr  = tt * 16 + r;
                    const int swt = (tr & 15) << 4;
                    const uint16_t* hrow = &Hs[tr * 256];
                    f32x4 c = {0.f, 0.f, 0.f, 0.f};
                    #pragma unroll
                    for (int kq = 0; kq < 8; ++kq) {
                        const bf16x8 a = *(const bf16x8*)&hrow[(kq * 32 + q * 8) ^ swt];
                        c = __builtin_amdgcn_mfma_f32_16x16x32_bf16(a, bfr[kq], c, 0, 0, 0);
                    }
                    #pragma unroll
                    for (int jj = 0; jj < 4; ++jj)
                        out[((size_t)b * NTOK + n0 + tt * 16 + q * 4 + jj) * 84 + w * 16 + r]
                            = c[jj] + bo_l;
                }
            }
        } else {
            if (w < 4) {
                const uint16_t* Bw = wbf + WOFF_BWO + r * 256 + q * 8;
                const int tr  = w * 16 + r;
                const int swt = (tr & 15) << 4;
                const uint16_t* hrow = &Hs[tr * 256];
                f32x4 c = {0.f, 0.f, 0.f, 0.f};
                #pragma unroll
                for (int kq = 0; kq < 8; ++kq) {
                    const bf16x8 a   = *(const bf16x8*)&hrow[(kq * 32 + q * 8) ^ swt];
                    const bf16x8 bfr = *(const bf16x8*)(Bw + kq * 32);
                    c = __builtin_amdgcn_mfma_f32_16x16x32_bf16(a, bfr, c, 0, 0, 0);
                }
                if (r < 4) {   // real box outs 0..3 (padded Wo rows 4..15 are zero)
                    const float bo_l = box_bo[r];
                    const float inv  = 1.0f / (float)dim;
                    #pragma unroll
                    for (int jj = 0; jj < 4; ++jj) {
                        const int t2 = w * 16 + q * 4 + jj;
                        const int p  = p0 + t2;
                        const float d = tanhf(c[jj] + bo_l);
                        float val;
                        if (r == 0)      val = ((float)(p & (dim - 1)) + 0.5f) * inv + 0.1f * d;
                        else if (r == 1) val = ((float)(p >> ls) + 0.5f) * inv + 0.1f * d;
                        else             val = exp2f(d) * inv;
                        out[((size_t)b * NTOK + n0 + t2) * 84 + 80 + r] = val;
                    }
                }
            }
        }
        // no barrier here: next stage writes Xs (disjoint from Hs); barrier 1 of the
        // next iteration orders epilogue(next) after all waves finish G2(this).
    }
}

extern "C" void kernel_launch(void* const* d_in, const int* in_sizes, int n_in,
                              void* d_out, int out_size, void* d_ws, size_t ws_size,
                              hipStream_t stream) {
    uint16_t* ws = (uint16_t*)d_ws;
    prep_weights<<<608, 256, 0, stream>>>(
        (const float*)d_in[5],  (const float*)d_in[7],
        (const float*)d_in[9],  (const float*)d_in[11], ws);
    // x: 43 groups of 16 = (8 tiles x 2 heads); y: 2 batch-quads
    dim3 grid(43 * 16, 2);
    dfd_head<<<grid, 512, 0, stream>>>(
        (const float*)d_in[0], (const float*)d_in[1], (const float*)d_in[2],
        (const float*)d_in[3], (const float*)d_in[4],
        (const float*)d_in[6],  (const float*)d_in[8],
        (const float*)d_in[10], (const float*)d_in[12],
        ws, (float*)d_out);
}

// Round 18
// 109.866 us; speedup vs baseline: 3.1700x; 3.1700x over previous
//
#include <hip/hip_runtime.h>
#include <hip/hip_bf16.h>
#include <math.h>
#include <stdint.h>

#define NTOK 21824
#define NTILE128 171     // 170 full 128-token tiles + 1 tail (64 tokens)

typedef __attribute__((ext_vector_type(8)))  short bf16x8;
typedef __attribute__((ext_vector_type(4)))  float f32x4;
typedef __attribute__((ext_vector_type(16))) float f32x16;

__device__ __forceinline__ uint32_t f2bf(float f) {
    uint32_t u = __builtin_bit_cast(uint32_t, f);
    return (u + 0x7FFFu + ((u >> 16) & 1u)) >> 16;   // RNE
}
__device__ __forceinline__ uint32_t pkbf2(float lo, float hi) {
    __hip_bfloat162 h = __float22bfloat162_rn(float2{lo, hi});
    uint32_t r; __builtin_memcpy(&r, &h, 4);         // v_cvt_pk_bf16_f32
    return r;
}

// ws layout (uint16): cls_Wh @0, box_Wh @65536, cls_Wo @131072, box_Wo(pad 16x256) @151552
#define WOFF_CWH 0
#define WOFF_BWH 65536
#define WOFF_CWO 131072
#define WOFF_BWO 151552

__global__ void prep_weights(const float* __restrict__ cWh, const float* __restrict__ cWo,
                             const float* __restrict__ bWh, const float* __restrict__ bWo,
                             uint16_t* __restrict__ ws) {
    int i = blockIdx.x * 256 + threadIdx.x;
    if (i >= 155648) return;
    uint32_t v;
    if (i < 65536)       v = f2bf(cWh[i]);
    else if (i < 131072) v = f2bf(bWh[i - 65536]);
    else if (i < 151552) v = f2bf(cWo[i - 131072]);
    else { int j = i - 151552; v = (j < 1024) ? f2bf(bWo[j]) : 0u; }
    ws[i] = (uint16_t)v;
}

// Head-split block: 128 tokens x ONE head. 8 waves, 64 KB LDS overlay.
// Stage: 16 float4 token-contiguous loads/thread (batched, one drain) vs 64 scalar.
__global__ __launch_bounds__(512, 4) void dfd_head(
    const float* __restrict__ fm0, const float* __restrict__ fm1,
    const float* __restrict__ fm2, const float* __restrict__ fm3,
    const float* __restrict__ fm4,
    const float* __restrict__ cls_bh, const float* __restrict__ cls_bo,
    const float* __restrict__ box_bh, const float* __restrict__ box_bo,
    const uint16_t* __restrict__ wbf,
    float* __restrict__ out)
{
    // decode (tile, head): twins (s, s+8) share id%8 -> same XCD for X L2 sharing
    const int g    = blockIdx.x;
    const int s    = g & 15;
    const int tile = (g >> 4) * 8 + (s & 7);
    const int head = s >> 3;                 // 0 = cls, 1 = box
    if (tile >= NTILE128) return;            // block-uniform

    __shared__ uint16_t LB[128 * 256];       // 64 KB overlay: Xs then Hs
    uint16_t* Xs = LB;
    uint16_t* Hs = LB;

    const int tid  = threadIdx.x;
    const int lane = tid & 63;
    const int w    = tid >> 6;               // wave 0..7
    const int r    = lane & 15;
    const int q    = lane >> 4;
    const int col  = lane & 31;
    const int hi   = lane >> 5;
    const int n0   = tile * 128;
    const int b    = blockIdx.y;

    const float* fm; int off, ls;
    if      (n0 < 16384) { fm = fm0; off = 0;     ls = 7; }
    else if (n0 < 20480) { fm = fm1; off = 16384; ls = 6; }
    else if (n0 < 21504) { fm = fm2; off = 20480; ls = 5; }
    else if (n0 < 21760) { fm = fm3; off = 21504; ls = 4; }
    else                 { fm = fm4; off = 21760; ls = 3; }
    const int dim = 1 << ls;
    const int hw  = 1 << (2 * ls);
    const int p0  = n0 - off;
    const int T   = (n0 == 21760) ? 64 : 128;   // tail tile has 64 tokens
    const int NT16 = T >> 4;

    // ---- stage: thread = (tg = tid&31 -> tokens tg*4..+3, fg = tid>>5 -> 16 features).
    //      16 coalesced float4 loads (batched), then cvt_pk + 8 b128 LDS writes.
    {
        const int tg = tid & 31;
        const int fg = tid >> 5;
        const int t0 = tg * 4;
        if (t0 < T) {
            const float* src = fm + (size_t)b * 256 * hw + p0 + t0;
            f32x4 xv[16];
            #pragma unroll
            for (int ff = 0; ff < 16; ++ff)
                xv[ff] = *(const f32x4*)(src + (size_t)(fg * 16 + ff) * hw);
            #pragma unroll
            for (int e = 0; e < 4; ++e) {
                const int t  = t0 + e;
                const int sw = (t & 31) << 3;
                const int f0 = fg * 16;
                uint4 pk1, pk2;
                pk1.x = pkbf2(xv[0][e],  xv[1][e]);  pk1.y = pkbf2(xv[2][e],  xv[3][e]);
                pk1.z = pkbf2(xv[4][e],  xv[5][e]);  pk1.w = pkbf2(xv[6][e],  xv[7][e]);
                pk2.x = pkbf2(xv[8][e],  xv[9][e]);  pk2.y = pkbf2(xv[10][e], xv[11][e]);
                pk2.z = pkbf2(xv[12][e], xv[13][e]); pk2.w = pkbf2(xv[14][e], xv[15][e]);
                *reinterpret_cast<uint4*>(&Xs[t * 256 + ((f0)     ^ sw)]) = pk1;
                *reinterpret_cast<uint4*>(&Xs[t * 256 + ((f0 + 8) ^ sw)]) = pk2;
            }
        }
    }
    __syncthreads();

    // ---- G1 (32x32x16): C[h][t]. Wave w owns hh [w*32, w*32+32) of this head.
    //      (r15-verified, byte-identical)
    f32x16 acc[4];   // [nt = token 32-tile]
    {
        #pragma unroll
        for (int nt = 0; nt < 4; ++nt)
            #pragma unroll
            for (int e = 0; e < 16; ++e) acc[nt][e] = 0.f;

        const int hhw = w * 32;
        const uint16_t* Wbase = wbf + (head ? WOFF_BWH : WOFF_CWH) + hhw * 256;
        const int kh = hi * 8;
        const uint16_t* Wr = Wbase + col * 256 + kh;   // A row = hhw + col
        const int sw0 = col << 3;

        #pragma unroll
        for (int ks = 0; ks < 16; ++ks) {
            const bf16x8 a = *(const bf16x8*)(Wr + ks * 16);
            const int kx = (ks * 16 + kh) ^ sw0;
            #pragma unroll
            for (int nt = 0; nt < 4; ++nt) {
                const bf16x8 x = *(const bf16x8*)&Xs[(nt * 32 + col) * 256 + kx];
                acc[nt] = __builtin_amdgcn_mfma_f32_32x32x16_bf16(a, x, acc[nt], 0, 0, 0);
            }
        }
    }
    __syncthreads();   // all Xs reads done before Hs overwrites

    // ---- epilogue: bias+ReLU, pack 4 consecutive hh per b64 write (r15-verified)
    {
        const int hhw = w * 32;
        const float* bh_ = (head ? box_bh : cls_bh) + hhw;
        #pragma unroll
        for (int nt = 0; nt < 4; ++nt) {
            const int t   = nt * 32 + col;
            const int swt = (t & 15) << 4;
            #pragma unroll
            for (int g2 = 0; g2 < 4; ++g2) {
                const int hb = 8 * g2 + 4 * hi;      // C row = hb + (reg&3)
                const f32x4 bv = *(const f32x4*)(bh_ + hb);
                const float v0 = fmaxf(acc[nt][4 * g2 + 0] + bv[0], 0.f);
                const float v1 = fmaxf(acc[nt][4 * g2 + 1] + bv[1], 0.f);
                const float v2 = fmaxf(acc[nt][4 * g2 + 2] + bv[2], 0.f);
                const float v3 = fmaxf(acc[nt][4 * g2 + 3] + bv[3], 0.f);
                uint2 pk; pk.x = pkbf2(v0, v1); pk.y = pkbf2(v2, v3);
                *reinterpret_cast<uint2*>(&Hs[t * 256 + ((hhw + hb) ^ swt)]) = pk;
            }
        }
    }
    __syncthreads();

    // ---- G2 (16x16x32), unchanged from r15
    if (head == 0) {
        if (w < 5) {
            const uint16_t* Bw = wbf + WOFF_CWO + (w * 16 + r) * 256 + q * 8;
            bf16x8 bfr[8];
            #pragma unroll
            for (int kq = 0; kq < 8; ++kq) bfr[kq] = *(const bf16x8*)(Bw + kq * 32);
            const float bo_l = cls_bo[w * 16 + r];
            #pragma unroll
            for (int tt = 0; tt < 8; ++tt) {
                if (tt < NT16) {
                    const int tr  = tt * 16 + r;
                    const int swt = (tr & 15) << 4;
                    const uint16_t* hrow = &Hs[tr * 256];
                    f32x4 c = {0.f, 0.f, 0.f, 0.f};
                    #pragma unroll
                    for (int kq = 0; kq < 8; ++kq) {
                        const bf16x8 a = *(const bf16x8*)&hrow[(kq * 32 + q * 8) ^ swt];
                        c = __builtin_amdgcn_mfma_f32_16x16x32_bf16(a, bfr[kq], c, 0, 0, 0);
                    }
                    #pragma unroll
                    for (int jj = 0; jj < 4; ++jj)
                        out[((size_t)b * NTOK + n0 + tt * 16 + q * 4 + jj) * 84 + w * 16 + r]
                            = c[jj] + bo_l;
                }
            }
        }
    } else {
        if (w < NT16) {
            const uint16_t* Bw = wbf + WOFF_BWO + r * 256 + q * 8;
            const int tr  = w * 16 + r;
            const int swt = (tr & 15) << 4;
            const uint16_t* hrow = &Hs[tr * 256];
            f32x4 c = {0.f, 0.f, 0.f, 0.f};
            #pragma unroll
            for (int kq = 0; kq < 8; ++kq) {
                const bf16x8 a   = *(const bf16x8*)&hrow[(kq * 32 + q * 8) ^ swt];
                const bf16x8 bfr = *(const bf16x8*)(Bw + kq * 32);
                c = __builtin_amdgcn_mfma_f32_16x16x32_bf16(a, bfr, c, 0, 0, 0);
            }
            if (r < 4) {
                const float bo_l = box_bo[r];
                const float inv  = 1.0f / (float)dim;
                #pragma unroll
                for (int jj = 0; jj < 4; ++jj) {
                    const int t2 = w * 16 + q * 4 + jj;
                    const int p  = p0 + t2;
                    const float d = tanhf(c[jj] + bo_l);
                    float val;
                    if (r == 0)      val = ((float)(p & (dim - 1)) + 0.5f) * inv + 0.1f * d;
                    else if (r == 1) val = ((float)(p >> ls) + 0.5f) * inv + 0.1f * d;
                    else             val = exp2f(d) * inv;
                    out[((size_t)b * NTOK + n0 + t2) * 84 + 80 + r] = val;
                }
            }
        }
    }
}

extern "C" void kernel_launch(void* const* d_in, const int* in_sizes, int n_in,
                              void* d_out, int out_size, void* d_ws, size_t ws_size,
                              hipStream_t stream) {
    uint16_t* ws = (uint16_t*)d_ws;
    prep_weights<<<608, 256, 0, stream>>>(
        (const float*)d_in[5],  (const float*)d_in[7],
        (const float*)d_in[9],  (const float*)d_in[11], ws);
    dim3 grid(22 * 16, 8);
    dfd_head<<<grid, 512, 0, stream>>>(
        (const float*)d_in[0], (const float*)d_in[1], (const float*)d_in[2],
        (const float*)d_in[3], (const float*)d_in[4],
        (const float*)d_in[6],  (const float*)d_in[8],
        (const float*)d_in[10], (const float*)d_in[12],
        ws, (float*)d_out);
}